// Round 1
// baseline (377.817 us; speedup 1.0000x reference)
//
#include <hip/hip_runtime.h>
#include <cstdint>
#include <cstddef>

#define V_N 50257
#define N_PAD 50304   // 393 * 128
#define D_K 512
#define M_T 512       // B*S

typedef __attribute__((ext_vector_type(8))) short bf16x8;
typedef __attribute__((ext_vector_type(4))) float f32x4;
typedef __attribute__((address_space(1))) const unsigned int as1_cuint;
typedef __attribute__((address_space(3))) unsigned int as3_uint;

__device__ __forceinline__ unsigned short f2bf(float f){
  unsigned int x = __float_as_uint(f);
  return (unsigned short)((x + 0x7fffu + ((x >> 16) & 1u)) >> 16);  // RNE
}

__device__ __forceinline__ void g2l16(const void* gp, void* lp){
  // async global->LDS, 16B/lane; LDS dest = uniform base + lane*16
  __builtin_amdgcn_global_load_lds((as1_cuint*)gp, (as3_uint*)lp, 16, 0, 0);
}

// ---------------- kernel 1: normalized emb rows -> bf16 (pad rows zeroed) ----
__global__ __launch_bounds__(64) void k_norm_emb(const float* __restrict__ emb,
                                                 unsigned short* __restrict__ ebf){
  const int v = blockIdx.x;
  const int lane = threadIdx.x;
  uint4* dst = (uint4*)(ebf + (size_t)v * D_K + lane * 8);
  if (v >= V_N){ *dst = make_uint4(0u, 0u, 0u, 0u); return; }
  const float* row = emb + (size_t)v * D_K + lane * 8;
  float4 a = *(const float4*)row;
  float4 b = *(const float4*)(row + 4);
  float ss = a.x*a.x + a.y*a.y + a.z*a.z + a.w*a.w
           + b.x*b.x + b.y*b.y + b.z*b.z + b.w*b.w;
  #pragma unroll
  for (int off = 32; off; off >>= 1) ss += __shfl_xor(ss, off, 64);
  float inv = 1.0f / fmaxf(sqrtf(ss), 1e-8f);
  uint4 w;
  w.x = (unsigned int)f2bf(a.x*inv) | ((unsigned int)f2bf(a.y*inv) << 16);
  w.y = (unsigned int)f2bf(a.z*inv) | ((unsigned int)f2bf(a.w*inv) << 16);
  w.z = (unsigned int)f2bf(b.x*inv) | ((unsigned int)f2bf(b.y*inv) << 16);
  w.w = (unsigned int)f2bf(b.z*inv) | ((unsigned int)f2bf(b.w*inv) << 16);
  *dst = w;
}

// ---------------- kernel 2: perturbed = emb[utt] + eps*sign(grad), normalize -> bf16
__global__ __launch_bounds__(64) void k_perturb(const int* __restrict__ utt,
                                                const float* __restrict__ emb,
                                                const float* __restrict__ grad,
                                                unsigned short* __restrict__ pbf){
  const int t = blockIdx.x;
  const int lane = threadIdx.x;
  const int u = utt[t];
  const float* e = emb + (size_t)u * D_K + lane * 8;
  const float* g = grad + (size_t)t * D_K + lane * 8;
  float p[8]; float ss = 0.f;
  #pragma unroll
  for (int j = 0; j < 8; ++j){
    float gv = g[j];
    float s = (gv > 0.f) ? 1.f : ((gv < 0.f) ? -1.f : 0.f);   // jnp.sign semantics
    p[j] = e[j] + 0.4f * s;
    ss += p[j] * p[j];
  }
  #pragma unroll
  for (int off = 32; off; off >>= 1) ss += __shfl_xor(ss, off, 64);
  float inv = 1.0f / fmaxf(sqrtf(ss), 1e-8f);
  uint4 w;
  w.x = (unsigned int)f2bf(p[0]*inv) | ((unsigned int)f2bf(p[1]*inv) << 16);
  w.y = (unsigned int)f2bf(p[2]*inv) | ((unsigned int)f2bf(p[3]*inv) << 16);
  w.z = (unsigned int)f2bf(p[4]*inv) | ((unsigned int)f2bf(p[5]*inv) << 16);
  w.w = (unsigned int)f2bf(p[6]*inv) | ((unsigned int)f2bf(p[7]*inv) << 16);
  *(uint4*)(pbf + (size_t)t * D_K + lane * 8) = w;
}

// ---------------- kernel 3: sim = Pbf [512x512] x Ebf^T [50304x512], fp32 out
// 128x128 block tile, BK=64, 4 waves each 64x64 (4x4 of 16x16x32 MFMA).
// LDS layout: 16B chunks, physical chunk (row r, group g) at r*8 + (g ^ (r&7))
// -> lane-linear for global_load_lds, 2-way-max bank aliasing on ds_read_b128.
__global__ __launch_bounds__(256) void k_gemm(const unsigned short* __restrict__ pbf,
                                              const unsigned short* __restrict__ ebf,
                                              float* __restrict__ sim){
  __shared__ __align__(16) unsigned short lds[16384]; // A: chunks 0..1023, B: 1024..2047
  const int tid  = threadIdx.x;
  const int wave = tid >> 6, lane = tid & 63;
  const int bn = blockIdx.x, bm = blockIdx.y;
  const int wm = (wave >> 1) * 64, wn = (wave & 1) * 64;

  const char* Ab = (const char*)pbf;
  const char* Bb = (const char*)ebf;
  size_t gA[4], gB[4];
  #pragma unroll
  for (int c = 0; c < 4; ++c){
    int p  = wave * 256 + c * 64 + lane;   // chunk id 0..1023
    int r  = p >> 3;                       // tile row 0..127
    int gl = (p & 7) ^ (r & 7);            // logical k-group for this physical slot
    gA[c] = (size_t)(bm * 128 + r) * 1024 + (size_t)gl * 16;
    gB[c] = (size_t)(bn * 128 + r) * 1024 + (size_t)gl * 16;
  }

  f32x4 acc[4][4];
  #pragma unroll
  for (int i = 0; i < 4; ++i)
    #pragma unroll
    for (int j = 0; j < 4; ++j)
      #pragma unroll
      for (int k = 0; k < 4; ++k) acc[i][j][k] = 0.f;

  const bf16x8* ch = (const bf16x8*)lds;
  const int la = lane & 15, lh = lane >> 4, lx = lane & 7;

  for (int kt = 0; kt < 8; ++kt){
    if (kt) __syncthreads();
    #pragma unroll
    for (int c = 0; c < 4; ++c)
      g2l16(Ab + gA[c] + (size_t)kt * 128, (void*)&lds[(wave * 256 + c * 64) * 8]);
    #pragma unroll
    for (int c = 0; c < 4; ++c)
      g2l16(Bb + gB[c] + (size_t)kt * 128, (void*)&lds[8192 + (wave * 256 + c * 64) * 8]);
    asm volatile("s_waitcnt vmcnt(0)" ::: "memory");
    __syncthreads();

    #pragma unroll
    for (int ks = 0; ks < 2; ++ks){
      bf16x8 af[4], bfr[4];
      #pragma unroll
      for (int mi = 0; mi < 4; ++mi){
        int r = wm + mi * 16 + la;                 // r&7 == lane&7
        af[mi] = ch[r * 8 + ((ks * 4 + lh) ^ lx)];
      }
      #pragma unroll
      for (int nj = 0; nj < 4; ++nj){
        int r = wn + nj * 16 + la;
        bfr[nj] = ch[1024 + r * 8 + ((ks * 4 + lh) ^ lx)];
      }
      #pragma unroll
      for (int mi = 0; mi < 4; ++mi)
        #pragma unroll
        for (int nj = 0; nj < 4; ++nj)
          acc[mi][nj] = __builtin_amdgcn_mfma_f32_16x16x32_bf16(af[mi], bfr[nj], acc[mi][nj], 0, 0, 0);
    }
  }

  // epilogue: C/D layout col=lane&15 (N), row=(lane>>4)*4+reg (M)
  #pragma unroll
  for (int mi = 0; mi < 4; ++mi){
    #pragma unroll
    for (int r = 0; r < 4; ++r){
      int trow = bm * 128 + wm + mi * 16 + lh * 4 + r;
      float* dst = sim + (size_t)trow * V_N;
      #pragma unroll
      for (int nj = 0; nj < 4; ++nj){
        int col = bn * 128 + wn + nj * 16 + la;
        if (col < V_N) dst[col] = acc[mi][nj][r];
      }
    }
  }
}

// ---------------- kernel 4: tie-aware argmax per token row -------------------
__global__ __launch_bounds__(256) void k_argmax(const float* __restrict__ sim,
                                                const float* __restrict__ noise,
                                                float* __restrict__ outIdx){
  const int t = blockIdx.x;
  const int tid = threadIdx.x;
  const float* row  = sim   + (size_t)t * V_N;
  const float* nrow = noise + (size_t)t * V_N;
  float bs = -3.0e38f, bnz = -3.0e38f; int bi = 0x7fffffff;
  for (int v = tid; v < V_N; v += 256){
    float s = row[v];
    if (s > bs){ bs = s; bi = v; bnz = nrow[v]; }          // lazy noise load
    else if (s == bs){
      float n = nrow[v];
      if (n > bnz || (n == bnz && v < bi)){ bnz = n; bi = v; }
    }
  }
  __shared__ float ss[256]; __shared__ float sn[256]; __shared__ int si[256];
  ss[tid] = bs; sn[tid] = bnz; si[tid] = bi;
  __syncthreads();
  for (int st = 128; st > 0; st >>= 1){
    if (tid < st){
      float os = ss[tid + st], on = sn[tid + st]; int oi = si[tid + st];
      float cs = ss[tid],      cn = sn[tid];      int ci = si[tid];
      bool take = (os > cs) || (os == cs && (on > cn || (on == cn && oi < ci)));
      if (take){ ss[tid] = os; sn[tid] = on; si[tid] = oi; }
    }
    __syncthreads();
  }
  if (tid == 0) outIdx[t] = (float)si[0];
}

extern "C" void kernel_launch(void* const* d_in, const int* in_sizes, int n_in,
                              void* d_out, int out_size, void* d_ws, size_t ws_size,
                              hipStream_t stream){
  const int*   utt   = (const int*)d_in[0];
  const float* emb   = (const float*)d_in[1];
  const float* grad  = (const float*)d_in[2];
  const float* noise = (const float*)d_in[3];
  float* out = (float*)d_out;                  // [512] new_utterance ++ [512*50257] sim

  unsigned short* ebf = (unsigned short*)d_ws;                 // 50304*512 bf16
  unsigned short* pbf = ebf + (size_t)N_PAD * D_K;             // 512*512 bf16

  hipLaunchKernelGGL(k_norm_emb, dim3(N_PAD), dim3(64), 0, stream, emb, ebf);
  hipLaunchKernelGGL(k_perturb,  dim3(M_T),  dim3(64), 0, stream, utt, emb, grad, pbf);
  hipLaunchKernelGGL(k_gemm,     dim3(393, 4), dim3(256), 0, stream, pbf, ebf, out + M_T);
  hipLaunchKernelGGL(k_argmax,   dim3(M_T),  dim3(256), 0, stream, out + M_T, noise, out);
}

// Round 2
// 290.525 us; speedup vs baseline: 1.3005x; 1.3005x over previous
//
#include <hip/hip_runtime.h>
#include <cstdint>
#include <cstddef>

#define V_N 50257
#define N_PAD 50304   // 393 * 128
#define D_K 512
#define M_T 512       // B*S
#define NPART 786     // 393 bn * 2 wave-col-halves

typedef __attribute__((ext_vector_type(8))) short bf16x8;
typedef __attribute__((ext_vector_type(4))) float f32x4;
typedef __attribute__((address_space(1))) const unsigned int as1_cuint;
typedef __attribute__((address_space(3))) unsigned int as3_uint;

#define NEG_INF -3.0e38f
#define TIE_BIT 0x80000000u

__device__ __forceinline__ unsigned short f2bf(float f){
  unsigned int x = __float_as_uint(f);
  return (unsigned short)((x + 0x7fffu + ((x >> 16) & 1u)) >> 16);  // RNE
}

__device__ __forceinline__ void g2l16(const void* gp, void* lp){
  __builtin_amdgcn_global_load_lds((as1_cuint*)gp, (as3_uint*)lp, 16, 0, 0);
}

// ---------------- kernel 1: normalized emb rows -> bf16 (pad rows zeroed) ----
__global__ __launch_bounds__(64) void k_norm_emb(const float* __restrict__ emb,
                                                 unsigned short* __restrict__ ebf){
  const int v = blockIdx.x;
  const int lane = threadIdx.x;
  uint4* dst = (uint4*)(ebf + (size_t)v * D_K + lane * 8);
  if (v >= V_N){ *dst = make_uint4(0u, 0u, 0u, 0u); return; }
  const float* row = emb + (size_t)v * D_K + lane * 8;
  float4 a = *(const float4*)row;
  float4 b = *(const float4*)(row + 4);
  float ss = a.x*a.x + a.y*a.y + a.z*a.z + a.w*a.w
           + b.x*b.x + b.y*b.y + b.z*b.z + b.w*b.w;
  #pragma unroll
  for (int off = 32; off; off >>= 1) ss += __shfl_xor(ss, off, 64);
  float inv = 1.0f / fmaxf(sqrtf(ss), 1e-8f);
  uint4 w;
  w.x = (unsigned int)f2bf(a.x*inv) | ((unsigned int)f2bf(a.y*inv) << 16);
  w.y = (unsigned int)f2bf(a.z*inv) | ((unsigned int)f2bf(a.w*inv) << 16);
  w.z = (unsigned int)f2bf(b.x*inv) | ((unsigned int)f2bf(b.y*inv) << 16);
  w.w = (unsigned int)f2bf(b.z*inv) | ((unsigned int)f2bf(b.w*inv) << 16);
  *dst = w;
}

// ---------------- kernel 2: perturbed = emb[utt] + eps*sign(grad), normalize -> bf16
__global__ __launch_bounds__(64) void k_perturb(const int* __restrict__ utt,
                                                const float* __restrict__ emb,
                                                const float* __restrict__ grad,
                                                unsigned short* __restrict__ pbf){
  const int t = blockIdx.x;
  const int lane = threadIdx.x;
  const int u = utt[t];
  const float* e = emb + (size_t)u * D_K + lane * 8;
  const float* g = grad + (size_t)t * D_K + lane * 8;
  float p[8]; float ss = 0.f;
  #pragma unroll
  for (int j = 0; j < 8; ++j){
    float gv = g[j];
    float s = (gv > 0.f) ? 1.f : ((gv < 0.f) ? -1.f : 0.f);   // jnp.sign semantics
    p[j] = e[j] + 0.4f * s;
    ss += p[j] * p[j];
  }
  #pragma unroll
  for (int off = 32; off; off >>= 1) ss += __shfl_xor(ss, off, 64);
  float inv = 1.0f / fmaxf(sqrtf(ss), 1e-8f);
  uint4 w;
  w.x = (unsigned int)f2bf(p[0]*inv) | ((unsigned int)f2bf(p[1]*inv) << 16);
  w.y = (unsigned int)f2bf(p[2]*inv) | ((unsigned int)f2bf(p[3]*inv) << 16);
  w.z = (unsigned int)f2bf(p[4]*inv) | ((unsigned int)f2bf(p[5]*inv) << 16);
  w.w = (unsigned int)f2bf(p[6]*inv) | ((unsigned int)f2bf(p[7]*inv) << 16);
  *(uint4*)(pbf + (size_t)t * D_K + lane * 8) = w;
}

// ---------------- kernel 3: sim = Pbf [512x512] x Ebf^T [50304x512], fp32 out
// + fused per-(row, 64-col-slice) argmax partials (max, idx, tie-bit)
__global__ __launch_bounds__(256) void k_gemm(const unsigned short* __restrict__ pbf,
                                              const unsigned short* __restrict__ ebf,
                                              float* __restrict__ sim,
                                              float* __restrict__ pmax,
                                              unsigned int* __restrict__ pmeta){
  __shared__ __align__(16) unsigned short lds[16384]; // A: chunks 0..1023, B: 1024..2047
  const int tid  = threadIdx.x;
  const int wave = tid >> 6, lane = tid & 63;
  const int bn = blockIdx.x, bm = blockIdx.y;
  const int wm = (wave >> 1) * 64, wn = (wave & 1) * 64;

  const char* Ab = (const char*)pbf;
  const char* Bb = (const char*)ebf;
  size_t gA[4], gB[4];
  #pragma unroll
  for (int c = 0; c < 4; ++c){
    int p  = wave * 256 + c * 64 + lane;   // chunk id 0..1023
    int r  = p >> 3;                       // tile row 0..127
    int gl = (p & 7) ^ (r & 7);            // logical k-group for this physical slot
    gA[c] = (size_t)(bm * 128 + r) * 1024 + (size_t)gl * 16;
    gB[c] = (size_t)(bn * 128 + r) * 1024 + (size_t)gl * 16;
  }

  f32x4 acc[4][4];
  #pragma unroll
  for (int i = 0; i < 4; ++i)
    #pragma unroll
    for (int j = 0; j < 4; ++j)
      #pragma unroll
      for (int k = 0; k < 4; ++k) acc[i][j][k] = 0.f;

  const bf16x8* ch = (const bf16x8*)lds;
  const int la = lane & 15, lh = lane >> 4, lx = lane & 7;

  for (int kt = 0; kt < 8; ++kt){
    if (kt) __syncthreads();
    #pragma unroll
    for (int c = 0; c < 4; ++c)
      g2l16(Ab + gA[c] + (size_t)kt * 128, (void*)&lds[(wave * 256 + c * 64) * 8]);
    #pragma unroll
    for (int c = 0; c < 4; ++c)
      g2l16(Bb + gB[c] + (size_t)kt * 128, (void*)&lds[8192 + (wave * 256 + c * 64) * 8]);
    asm volatile("s_waitcnt vmcnt(0)" ::: "memory");
    __syncthreads();

    #pragma unroll
    for (int ks = 0; ks < 2; ++ks){
      bf16x8 af[4], bfr[4];
      #pragma unroll
      for (int mi = 0; mi < 4; ++mi){
        int r = wm + mi * 16 + la;                 // r&7 == lane&7
        af[mi] = ch[r * 8 + ((ks * 4 + lh) ^ lx)];
      }
      #pragma unroll
      for (int nj = 0; nj < 4; ++nj){
        int r = wn + nj * 16 + la;
        bfr[nj] = ch[1024 + r * 8 + ((ks * 4 + lh) ^ lx)];
      }
      #pragma unroll
      for (int mi = 0; mi < 4; ++mi)
        #pragma unroll
        for (int nj = 0; nj < 4; ++nj)
          acc[mi][nj] = __builtin_amdgcn_mfma_f32_16x16x32_bf16(af[mi], bfr[nj], acc[mi][nj], 0, 0, 0);
    }
  }

  // epilogue: C/D layout col=lane&15 (N), row=(lane>>4)*4+reg (M)
  const int pc = bn * 2 + (wn >> 6);   // partial column slot for this wave
  #pragma unroll
  for (int mi = 0; mi < 4; ++mi){
    #pragma unroll
    for (int r = 0; r < 4; ++r){
      int trow = bm * 128 + wm + mi * 16 + lh * 4 + r;
      float* dst = sim + (size_t)trow * V_N;
      // coalesced sim store
      #pragma unroll
      for (int nj = 0; nj < 4; ++nj){
        int col = bn * 128 + wn + nj * 16 + la;
        if (col < V_N) dst[col] = acc[mi][nj][r];
      }
      // branchless local argmax over this lane's 4 cols
      float bv = NEG_INF; unsigned int bmeta = 0u;
      #pragma unroll
      for (int nj = 0; nj < 4; ++nj){
        int col = bn * 128 + wn + nj * 16 + la;
        float v = (col < V_N) ? acc[mi][nj][r] : NEG_INF;
        bool gt = v > bv, eq = (v == bv);
        bmeta = gt ? (unsigned int)col : (bmeta | (eq ? TIE_BIT : 0u));
        bv = gt ? v : bv;
      }
      // reduce over the 16 'la' lanes (stay within the lh group: masks 1..8)
      #pragma unroll
      for (int m = 1; m <= 8; m <<= 1){
        float ov = __shfl_xor(bv, m, 64);
        unsigned int om = (unsigned int)__shfl_xor((int)bmeta, m, 64);
        bool gt = ov > bv, eq = (ov == bv);
        bmeta = gt ? om : (bmeta | (eq ? TIE_BIT : 0u));
        bv = gt ? ov : bv;
      }
      if (la == 0){
        pmax [(size_t)trow * NPART + pc] = bv;
        pmeta[(size_t)trow * NPART + pc] = bmeta;
      }
    }
  }
}

// ---------------- kernel 4: reduce partials; rare exact-tie path -------------
__global__ __launch_bounds__(256) void k_pick(const float* __restrict__ pmax,
                                              const unsigned int* __restrict__ pmeta,
                                              const float* __restrict__ sim,
                                              const float* __restrict__ noise,
                                              float* __restrict__ outIdx){
  const int t = blockIdx.x;
  const int tid = threadIdx.x;
  float bv = NEG_INF; unsigned int bmeta = 0u;
  for (int j = tid; j < NPART; j += 256){
    float v = pmax[(size_t)t * NPART + j];
    unsigned int m = pmeta[(size_t)t * NPART + j];
    bool gt = v > bv, eq = (v == bv);
    bmeta = gt ? m : (bmeta | (eq ? TIE_BIT : 0u));
    bv = gt ? v : bv;
  }
  __shared__ float ss[256]; __shared__ unsigned int sm[256];
  ss[tid] = bv; sm[tid] = bmeta;
  __syncthreads();
  for (int st = 128; st > 0; st >>= 1){
    if (tid < st){
      float ov = ss[tid + st]; unsigned int om = sm[tid + st];
      float cv = ss[tid];      unsigned int cm = sm[tid];
      bool gt = ov > cv, eq = (ov == cv);
      sm[tid] = gt ? om : (cm | (eq ? TIE_BIT : 0u));
      ss[tid] = gt ? ov : cv;
    }
    __syncthreads();
  }
  float gmax = ss[0];
  unsigned int gm = sm[0];
  if (!(gm & TIE_BIT)){
    if (tid == 0) outIdx[t] = (float)(gm & 0x7fffffffu);
    return;
  }
  // rare exact-tie path: rescan the row, exact reference comparator
  const float* row  = sim   + (size_t)t * V_N;
  const float* nrow = noise + (size_t)t * V_N;
  float bn2 = NEG_INF; int bi = 0x7fffffff;
  for (int v = tid; v < V_N; v += 256){
    if (row[v] == gmax){
      float n = nrow[v];
      if (n > bn2 || (n == bn2 && v < bi)){ bn2 = n; bi = v; }
    }
  }
  __shared__ float sn2[256]; __shared__ int si2[256];
  sn2[tid] = bn2; si2[tid] = bi;
  __syncthreads();
  for (int st = 128; st > 0; st >>= 1){
    if (tid < st){
      float on = sn2[tid + st]; int oi = si2[tid + st];
      float cn = sn2[tid];      int ci = si2[tid];
      bool take = (on > cn) || (on == cn && oi < ci);
      if (take){ sn2[tid] = on; si2[tid] = oi; }
    }
    __syncthreads();
  }
  if (tid == 0) outIdx[t] = (float)si2[0];
}

extern "C" void kernel_launch(void* const* d_in, const int* in_sizes, int n_in,
                              void* d_out, int out_size, void* d_ws, size_t ws_size,
                              hipStream_t stream){
  const int*   utt   = (const int*)d_in[0];
  const float* emb   = (const float*)d_in[1];
  const float* grad  = (const float*)d_in[2];
  const float* noise = (const float*)d_in[3];
  float* out = (float*)d_out;                  // [512] new_utterance ++ [512*50257] sim

  unsigned short* ebf = (unsigned short*)d_ws;                 // 50304*512 bf16
  unsigned short* pbf = ebf + (size_t)N_PAD * D_K;             // 512*512 bf16
  float*        pmax  = (float*)(pbf + (size_t)M_T * D_K);     // 512*786 f32
  unsigned int* pmeta = (unsigned int*)(pmax + (size_t)M_T * NPART); // 512*786 u32

  hipLaunchKernelGGL(k_norm_emb, dim3(N_PAD), dim3(64), 0, stream, emb, ebf);
  hipLaunchKernelGGL(k_perturb,  dim3(M_T),  dim3(64), 0, stream, utt, emb, grad, pbf);
  hipLaunchKernelGGL(k_gemm,     dim3(393, 4), dim3(256), 0, stream, pbf, ebf, out + M_T, pmax, pmeta);
  hipLaunchKernelGGL(k_pick,     dim3(M_T),  dim3(256), 0, stream, pmax, pmeta, out + M_T, noise, out);
}